// Round 8
// baseline (84.370 us; speedup 1.0000x reference)
//
#include <hip/hip_runtime.h>

#define D 64
#define EPSV 1e-9f

typedef __attribute__((ext_vector_type(8))) short bf8_t;   // 8 x bf16
typedef __attribute__((ext_vector_type(4))) float f4_t;

__device__ inline float bf2f(short u) {
    union { unsigned int i; float f; } v;
    v.i = ((unsigned int)(unsigned short)u) << 16;
    return v.f;
}
__device__ inline unsigned short f2bf(float f) {  // round-nearest-even
    union { float f; unsigned int i; } v; v.f = f;
    unsigned int r = v.i + 0x7fff + ((v.i >> 16) & 1);
    return (unsigned short)(r >> 16);
}

// --- Fused prep: cvt (blocks [0,cvtb)), wpack (next 32), row offsets (rest) ---
__global__ void prep_kernel(const float* __restrict__ node_feats,
                            const int*   __restrict__ edge_dst,
                            const float* __restrict__ W0,
                            const float* __restrict__ W1,
                            int* __restrict__ row_off,
                            unsigned short* __restrict__ Wpack,
                            unsigned short* __restrict__ X,   // [n][64] bf16
                            int n_nodes, int n_edges, int cvtb)
{
    const int bid = blockIdx.x;
    const int tid = threadIdx.x;
    if (bid < cvtb) {
        const int i = bid * 256 + tid;           // one per 4 floats
        if (i < n_nodes * 16) {
            const float4 v = ((const float4*)node_feats)[i];
            const int row = i >> 4, c4 = (i & 15) * 4;
            unsigned short* p = X + row * 64 + c4;
            p[0] = f2bf(v.x); p[1] = f2bf(v.y); p[2] = f2bf(v.z); p[3] = f2bf(v.w);
        }
    } else if (bid < cvtb + 32) {
        // Wpack[((t*4+kk)*64+lane)*8+j] = W[k][col], k=kk*32+(lane>>4)*8+j, col=t*16+(lane&15)
        const int idx = (bid - cvtb) * 256 + tid;
        const int j = idx & 7, lane = (idx >> 3) & 63, kk = (idx >> 9) & 3, t = idx >> 11;
        const int k = kk * 32 + (lane >> 4) * 8 + j;
        const int d = t * 16 + (lane & 15);
        const float v = (k < D) ? W0[d * D + k] : W1[d * D + (k - D)];
        Wpack[idx] = f2bf(v);
    } else {
        const int n = (bid - cvtb - 32) * 256 + tid;
        if (n <= n_nodes) {
            int lo = 0, hi = n_edges;
            while (lo < hi) {
                const int mid = (lo + hi) >> 1;
                if (edge_dst[mid] < n) lo = mid + 1; else hi = mid;
            }
            row_off[n] = lo;
        }
    }
}

// --- Aggregate: one wave per 4 nodes, NO inter-wave coupling.
// All meta for 32 edges x 4 nodes loaded upfront (16 loads in flight), then
// 16 independent row gathers. Rare tail loop for degree > 32.
__global__ __launch_bounds__(256, 4) void aggregate_kernel(
    const unsigned short* __restrict__ Xin,   // [n][64] bf16
    unsigned short* __restrict__ M,           // [n][64] bf16 msg out
    const int*   __restrict__ row_off,
    const int*   __restrict__ edge_src,
    const float* __restrict__ edge_w,
    int n_nodes)
{
    const int lane = threadIdx.x & 63;
    const int wib  = threadIdx.x >> 6;
    const int nb   = (blockIdx.x * 4 + wib) * 4;   // first of 4 nodes

    int s[4], e[4];
    #pragma unroll
    for (int i = 0; i < 4; ++i) {
        int n = nb + i; if (n >= n_nodes) n = n_nodes - 1;
        n = __builtin_amdgcn_readfirstlane(n);
        s[i] = row_off[n]; e[i] = row_off[n + 1];
    }

    const int slot = lane >> 3;        // 0..7
    const int fo   = (lane & 7) * 8;   // bf16 elem offset (16B chunk)

    // ---- batch meta: 4 groups of 8 edges per node, all independent ----
    float wM[4][4]; int sM[4][4];
    #pragma unroll
    for (int i = 0; i < 4; ++i)
        #pragma unroll
        for (int g = 0; g < 4; ++g) {
            const int  ej = s[i] + g * 8 + slot;
            const bool v  = ej < e[i];
            wM[i][g] = v ? edge_w[ej] : 0.f;
            sM[i][g] = v ? edge_src[ej] : 0;
        }

    float acc[4][8];
    float ws[4];
    #pragma unroll
    for (int i = 0; i < 4; ++i) {
        ws[i] = 0.f;
        #pragma unroll
        for (int m = 0; m < 8; ++m) acc[i][m] = 0.f;
    }

    // ---- 16 independent gathers ----
    #pragma unroll
    for (int i = 0; i < 4; ++i)
        #pragma unroll
        for (int g = 0; g < 4; ++g) {
            const bf8_t f = *(const bf8_t*)(Xin + sM[i][g] * 64 + fo);
            #pragma unroll
            for (int m = 0; m < 8; ++m)
                acc[i][m] = fmaf(wM[i][g], bf2f(f[m]), acc[i][m]);
            ws[i] += wM[i][g];
        }

    // ---- rare tail: degree > 32 ----
    int dmax = 0;
    #pragma unroll
    for (int i = 0; i < 4; ++i) { const int d = e[i] - s[i]; if (d > dmax) dmax = d; }
    for (int base = 32; base < dmax; base += 16) {
        #pragma unroll
        for (int i = 0; i < 4; ++i) {
            const int  ej0 = s[i] + base + slot;
            const int  ej1 = ej0 + 8;
            const bool v0 = ej0 < e[i], v1 = ej1 < e[i];
            const float w0 = v0 ? edge_w[ej0] : 0.f;
            const float w1 = v1 ? edge_w[ej1] : 0.f;
            const int  sc0 = v0 ? edge_src[ej0] : 0;
            const int  sc1 = v1 ? edge_src[ej1] : 0;
            const bf8_t f0 = *(const bf8_t*)(Xin + sc0 * 64 + fo);
            const bf8_t f1 = *(const bf8_t*)(Xin + sc1 * 64 + fo);
            #pragma unroll
            for (int m = 0; m < 8; ++m)
                acc[i][m] = fmaf(w0, bf2f(f0[m]), fmaf(w1, bf2f(f1[m]), acc[i][m]));
            ws[i] += w0 + w1;
        }
    }

    // butterfly over slot bits (lane bits 3,4,5)
    #pragma unroll
    for (int off = 8; off <= 32; off <<= 1) {
        #pragma unroll
        for (int i = 0; i < 4; ++i) {
            #pragma unroll
            for (int m = 0; m < 8; ++m) acc[i][m] += __shfl_xor(acc[i][m], off);
            ws[i] += __shfl_xor(ws[i], off);
        }
    }

    // lane-group g (0..3) writes node g's msg (static index via unroll)
    const int g = lane >> 3;
    #pragma unroll
    for (int i = 0; i < 4; ++i) {
        if (g == i) {
            int n = nb + i; if (n < n_nodes) {
                const float inv = 1.0f / (ws[i] + EPSV);
                bf8_t mv;
                #pragma unroll
                for (int m = 0; m < 8; ++m) mv[m] = (short)f2bf(acc[i][m] * inv);
                *(bf8_t*)(M + n * 64 + fo) = mv;
            }
        }
    }
}

// --- MFMA GEMM: out = relu([X | M] @ [W0';W1'] + b0 + b1). Wave = 16 rows x 64 cols.
template<int OUT_F32>
__global__ __launch_bounds__(256, 4) void gemm_mfma(
    const unsigned short* __restrict__ X,      // [n][64] bf16
    const unsigned short* __restrict__ M,      // [n][64] bf16
    const unsigned short* __restrict__ Wpack,  // fragment-packed, 8192 bf16
    const float* __restrict__ b0,
    const float* __restrict__ b1,
    void* __restrict__ outp,
    int ntiles, int waves_total, int n_nodes)
{
    const int lane = threadIdx.x & 63;
    const int wib  = threadIdx.x >> 6;
    const int wave = __builtin_amdgcn_readfirstlane(blockIdx.x * 4 + wib);

    bf8_t bfr[4][4];
    #pragma unroll
    for (int t = 0; t < 4; ++t)
        #pragma unroll
        for (int kk = 0; kk < 4; ++kk)
            bfr[t][kk] = *(const bf8_t*)(Wpack + ((t * 4 + kk) * 64 + lane) * 8);

    float bias[4];
    #pragma unroll
    for (int t = 0; t < 4; ++t) {
        const int col = t * 16 + (lane & 15);
        bias[t] = b0[col] + b1[col];
    }

    const int koff = (lane >> 4) * 8;

    for (int tile = wave; tile < ntiles; tile += waves_total) {
        const int rowbase = tile * 16;
        int arow = rowbase + (lane & 15); if (arow >= n_nodes) arow = n_nodes - 1;
        const unsigned short* ap = X + arow * 64 + koff;
        const unsigned short* mp = M + arow * 64 + koff;

        bf8_t af[4];
        af[0] = *(const bf8_t*)(ap);
        af[1] = *(const bf8_t*)(ap + 32);
        af[2] = *(const bf8_t*)(mp);
        af[3] = *(const bf8_t*)(mp + 32);

        f4_t acc[4];
        #pragma unroll
        for (int t = 0; t < 4; ++t) acc[t] = (f4_t){0.f, 0.f, 0.f, 0.f};

        #pragma unroll
        for (int t = 0; t < 4; ++t)
            #pragma unroll
            for (int kk = 0; kk < 4; ++kk)
                acc[t] = __builtin_amdgcn_mfma_f32_16x16x32_bf16(af[kk], bfr[t][kk], acc[t], 0, 0, 0);

        #pragma unroll
        for (int t = 0; t < 4; ++t) {
            const int col = t * 16 + (lane & 15);
            #pragma unroll
            for (int r = 0; r < 4; ++r) {
                const int row = rowbase + (lane >> 4) * 4 + r;
                if (row < n_nodes) {
                    const float v = fmaxf(acc[t][r] + bias[t], 0.0f);
                    if (OUT_F32) ((float*)outp)[row * 64 + col] = v;
                    else ((unsigned short*)outp)[row * 64 + col] = f2bf(v);
                }
            }
        }
    }
}

extern "C" void kernel_launch(void* const* d_in, const int* in_sizes, int n_in,
                              void* d_out, int out_size, void* d_ws, size_t ws_size,
                              hipStream_t stream) {
    const float* node_feats = (const float*)d_in[0];
    const int*   edge_src   = (const int*)  d_in[1];
    const int*   edge_dst   = (const int*)  d_in[2];
    const float* edge_w     = (const float*)d_in[3];
    const float* W0         = (const float*)d_in[4];
    const float* b0         = (const float*)d_in[5];
    const float* W1         = (const float*)d_in[6];
    const float* b1         = (const float*)d_in[7];

    const int n_nodes = in_sizes[0] / D;   // 50000
    const int n_edges = in_sizes[1];       // 800000

    // workspace layout (256B-aligned)
    char* ws = (char*)d_ws;
    int*            row_off = (int*)ws;                          // (n+1) ints
    unsigned short* Wpack   = (unsigned short*)(ws + 204800);    // 16 KB
    unsigned short* X0      = (unsigned short*)(ws + 237568);             // 6.4 MB
    unsigned short* X1      = (unsigned short*)(ws + 237568 + 6400000);   // 6.4 MB
    unsigned short* M       = (unsigned short*)(ws + 237568 + 12800000);  // 6.4 MB

    const int cvtb = (n_nodes * 16 + 255) / 256;    // 3125
    const int offb = (n_nodes + 1 + 255) / 256;     // 196
    prep_kernel<<<cvtb + 32 + offb, 256, 0, stream>>>(node_feats, edge_dst, W0, W1,
                                                      row_off, Wpack, X0,
                                                      n_nodes, n_edges, cvtb);

    const int agrid  = (n_nodes + 15) / 16;   // 4 nodes/wave * 4 waves
    const int ntiles = (n_nodes + 15) / 16;   // 3125
    const int ggrid  = 256;                   // 1024 waves
    const int gwaves = ggrid * 4;

    // layer 0
    aggregate_kernel<<<agrid, 256, 0, stream>>>(X0, M, row_off, edge_src, edge_w, n_nodes);
    gemm_mfma<0><<<ggrid, 256, 0, stream>>>(X0, M, Wpack, b0, b1, X1, ntiles, gwaves, n_nodes);
    // layer 1
    aggregate_kernel<<<agrid, 256, 0, stream>>>(X1, M, row_off, edge_src, edge_w, n_nodes);
    gemm_mfma<1><<<ggrid, 256, 0, stream>>>(X1, M, Wpack, b0, b1, d_out, ntiles, gwaves, n_nodes);
}

// Round 9
// 73.631 us; speedup vs baseline: 1.1458x; 1.1458x over previous
//
#include <hip/hip_runtime.h>

#define D 64
#define EPSV 1e-9f

typedef __attribute__((ext_vector_type(8))) short bf8_t;   // 8 x bf16
typedef __attribute__((ext_vector_type(4))) float f4_t;

__device__ inline float bf2f(short u) {
    union { unsigned int i; float f; } v;
    v.i = ((unsigned int)(unsigned short)u) << 16;
    return v.f;
}
__device__ inline unsigned short f2bf(float f) {  // round-nearest-even
    union { float f; unsigned int i; } v; v.f = f;
    unsigned int r = v.i + 0x7fff + ((v.i >> 16) & 1);
    return (unsigned short)(r >> 16);
}

// --- Fused prep: cvt (blocks [0,cvtb)), wpack (next 32), row offsets (rest) ---
__global__ void prep_kernel(const float* __restrict__ node_feats,
                            const int*   __restrict__ edge_dst,
                            const float* __restrict__ W0,
                            const float* __restrict__ W1,
                            int* __restrict__ row_off,
                            unsigned short* __restrict__ Wpack,
                            unsigned short* __restrict__ X,   // [n][128] bf16: x | msg
                            int n_nodes, int n_edges, int cvtb)
{
    const int bid = blockIdx.x;
    const int tid = threadIdx.x;
    if (bid < cvtb) {
        const int i = bid * 256 + tid;           // one per 4 floats
        if (i < n_nodes * 16) {
            const float4 v = ((const float4*)node_feats)[i];
            const int row = i >> 4, c4 = (i & 15) * 4;
            unsigned short* p = X + row * 128 + c4;
            p[0] = f2bf(v.x); p[1] = f2bf(v.y); p[2] = f2bf(v.z); p[3] = f2bf(v.w);
        }
    } else if (bid < cvtb + 32) {
        // Wpack[((t*4+kk)*64+lane)*8+j] = W[k][col], k=kk*32+(lane>>4)*8+j, col=t*16+(lane&15)
        const int idx = (bid - cvtb) * 256 + tid;
        const int j = idx & 7, lane = (idx >> 3) & 63, kk = (idx >> 9) & 3, t = idx >> 11;
        const int k = kk * 32 + (lane >> 4) * 8 + j;
        const int d = t * 16 + (lane & 15);
        const float v = (k < D) ? W0[d * D + k] : W1[d * D + (k - D)];
        Wpack[idx] = f2bf(v);
    } else {
        const int n = (bid - cvtb - 32) * 256 + tid;
        if (n <= n_nodes) {
            int lo = 0, hi = n_edges;
            while (lo < hi) {
                const int mid = (lo + hi) >> 1;
                if (edge_dst[mid] < n) lo = mid + 1; else hi = mid;
            }
            row_off[n] = lo;
        }
    }
}

// --- Aggregate: ONE node per wave, max occupancy (8 waves/SIMD, no LDS).
// 8 slots x 8 lanes x 16B. Meta for 4 groups loaded upfront; gathers for
// groups 0-1 always, 2-3 under wave-uniform deg>16 branch, uniform tail loop.
__global__ __launch_bounds__(256, 8) void aggregate_kernel(
    unsigned short* __restrict__ X,       // [n][128]: reads x, writes msg
    const int*   __restrict__ row_off,
    const int*   __restrict__ edge_src,
    const float* __restrict__ edge_w,
    int n_nodes)
{
    const int lane = threadIdx.x & 63;
    const int wib  = threadIdx.x >> 6;
    int node = blockIdx.x * 4 + wib;
    if (node >= n_nodes) node = n_nodes - 1;   // dup wave writes identical data
    node = __builtin_amdgcn_readfirstlane(node);

    const int s = row_off[node];
    const int e = row_off[node + 1];
    const int deg = e - s;

    const int slot = lane >> 3;        // 0..7
    const int fo   = (lane & 7) * 8;   // bf16 elem offset in x-part (16B chunk)

    // meta for 4 groups (32 edges), contiguous -> cheap even when partly dead
    float w[4]; int sc[4];
    #pragma unroll
    for (int g = 0; g < 4; ++g) {
        const int  ej = s + g * 8 + slot;
        const bool v  = ej < e;
        w[g]  = v ? edge_w[ej] : 0.f;
        sc[g] = v ? edge_src[ej] : 0;
    }

    float acc[8];
    #pragma unroll
    for (int m = 0; m < 8; ++m) acc[m] = 0.f;
    float wsum = 0.f;

    // groups 0-1: always (covers deg <= 16, the majority)
    {
        const bf8_t f0 = *(const bf8_t*)(X + sc[0] * 128 + fo);
        const bf8_t f1 = *(const bf8_t*)(X + sc[1] * 128 + fo);
        #pragma unroll
        for (int m = 0; m < 8; ++m)
            acc[m] = fmaf(w[0], bf2f(f0[m]), fmaf(w[1], bf2f(f1[m]), acc[m]));
        wsum += w[0] + w[1];
    }
    if (deg > 16) {   // wave-uniform branch (deg uniform per wave)
        const bf8_t f2 = *(const bf8_t*)(X + sc[2] * 128 + fo);
        const bf8_t f3 = *(const bf8_t*)(X + sc[3] * 128 + fo);
        #pragma unroll
        for (int m = 0; m < 8; ++m)
            acc[m] = fmaf(w[2], bf2f(f2[m]), fmaf(w[3], bf2f(f3[m]), acc[m]));
        wsum += w[2] + w[3];
    }
    // uniform tail: deg > 32 (rare)
    for (int base = 32; base < deg; base += 16) {
        const int  ej0 = s + base + slot;
        const int  ej1 = ej0 + 8;
        const bool v0 = ej0 < e, v1 = ej1 < e;
        const float w0 = v0 ? edge_w[ej0] : 0.f;
        const float w1 = v1 ? edge_w[ej1] : 0.f;
        const int  sc0 = v0 ? edge_src[ej0] : 0;
        const int  sc1 = v1 ? edge_src[ej1] : 0;
        const bf8_t f0 = *(const bf8_t*)(X + sc0 * 128 + fo);
        const bf8_t f1 = *(const bf8_t*)(X + sc1 * 128 + fo);
        #pragma unroll
        for (int m = 0; m < 8; ++m)
            acc[m] = fmaf(w0, bf2f(f0[m]), fmaf(w1, bf2f(f1[m]), acc[m]));
        wsum += w0 + w1;
    }

    // butterfly over slot bits (lane bits 3,4,5)
    #pragma unroll
    for (int off = 8; off <= 32; off <<= 1) {
        #pragma unroll
        for (int m = 0; m < 8; ++m) acc[m] += __shfl_xor(acc[m], off);
        wsum += __shfl_xor(wsum, off);
    }

    const float inv = 1.0f / (wsum + EPSV);
    if (lane < 8) {
        bf8_t mv;
        #pragma unroll
        for (int m = 0; m < 8; ++m) mv[m] = (short)f2bf(acc[m] * inv);
        *(bf8_t*)(X + node * 128 + 64 + fo) = mv;
    }
}

// --- MFMA GEMM: out = relu(X @ [W0';W1'] + b0 + b1). One wave = 16 rows x 64 cols.
template<int OUT_F32>
__global__ __launch_bounds__(256, 4) void gemm_mfma(
    const unsigned short* __restrict__ X,      // [rows][128] bf16
    const unsigned short* __restrict__ Wpack,  // fragment-packed, 8192 bf16
    const float* __restrict__ b0,
    const float* __restrict__ b1,
    void* __restrict__ outp,
    int ntiles, int waves_total)
{
    const int lane = threadIdx.x & 63;
    const int wib  = threadIdx.x >> 6;
    const int wave = __builtin_amdgcn_readfirstlane(blockIdx.x * 4 + wib);

    bf8_t bfr[4][4];
    #pragma unroll
    for (int t = 0; t < 4; ++t)
        #pragma unroll
        for (int kk = 0; kk < 4; ++kk)
            bfr[t][kk] = *(const bf8_t*)(Wpack + ((t * 4 + kk) * 64 + lane) * 8);

    float bias[4];
    #pragma unroll
    for (int t = 0; t < 4; ++t) {
        const int col = t * 16 + (lane & 15);
        bias[t] = b0[col] + b1[col];
    }

    for (int tile = wave; tile < ntiles; tile += waves_total) {
        const int rowbase = tile * 16;
        const int arow = rowbase + (lane & 15);
        const unsigned short* ap = X + arow * 128 + (lane >> 4) * 8;

        bf8_t af[4];
        #pragma unroll
        for (int kk = 0; kk < 4; ++kk) af[kk] = *(const bf8_t*)(ap + kk * 32);

        f4_t acc[4];
        #pragma unroll
        for (int t = 0; t < 4; ++t) acc[t] = (f4_t){0.f, 0.f, 0.f, 0.f};

        #pragma unroll
        for (int t = 0; t < 4; ++t)
            #pragma unroll
            for (int kk = 0; kk < 4; ++kk)
                acc[t] = __builtin_amdgcn_mfma_f32_16x16x32_bf16(af[kk], bfr[t][kk], acc[t], 0, 0, 0);

        #pragma unroll
        for (int t = 0; t < 4; ++t) {
            const int col = t * 16 + (lane & 15);
            #pragma unroll
            for (int r = 0; r < 4; ++r) {
                const float v = fmaxf(acc[t][r] + bias[t], 0.0f);
                const int row = rowbase + (lane >> 4) * 4 + r;
                if (OUT_F32) ((float*)outp)[row * 64 + col] = v;
                else ((unsigned short*)outp)[row * 128 + col] = f2bf(v);
            }
        }
    }
}

extern "C" void kernel_launch(void* const* d_in, const int* in_sizes, int n_in,
                              void* d_out, int out_size, void* d_ws, size_t ws_size,
                              hipStream_t stream) {
    const float* node_feats = (const float*)d_in[0];
    const int*   edge_src   = (const int*)  d_in[1];
    const int*   edge_dst   = (const int*)  d_in[2];
    const float* edge_w     = (const float*)d_in[3];
    const float* W0         = (const float*)d_in[4];
    const float* b0         = (const float*)d_in[5];
    const float* W1         = (const float*)d_in[6];
    const float* b1         = (const float*)d_in[7];

    const int n_nodes = in_sizes[0] / D;   // 50000
    const int n_edges = in_sizes[1];       // 800000

    // workspace layout
    char* ws = (char*)d_ws;
    int*            row_off = (int*)ws;                        // (n+1) ints
    unsigned short* Wpack   = (unsigned short*)(ws + 204800);  // 16384 B
    unsigned short* X0      = (unsigned short*)(ws + 237568);  // 12.8 MB
    unsigned short* X1      = (unsigned short*)d_out;          // aliases output

    const int cvtb = (n_nodes * 16 + 255) / 256;          // 3125
    const int offb = (n_nodes + 1 + 255) / 256;           // 196
    prep_kernel<<<cvtb + 32 + offb, 256, 0, stream>>>(node_feats, edge_dst, W0, W1,
                                                      row_off, Wpack, X0,
                                                      n_nodes, n_edges, cvtb);

    const int agrid  = (n_nodes + 3) / 4;       // 1 node/wave, 4 waves/block
    const int ntiles = (n_nodes + 15) / 16;     // 3125
    const int ggrid  = 256;                     // 1024 waves
    const int gwaves = ggrid * 4;

    // layer 0
    aggregate_kernel<<<agrid, 256, 0, stream>>>(X0, row_off, edge_src, edge_w, n_nodes);
    gemm_mfma<0><<<ggrid, 256, 0, stream>>>(X0, Wpack, b0, b1, X1, ntiles, gwaves);
    // layer 1 (X1 aliases d_out; final gemm reads its own rows before overwriting f32)
    aggregate_kernel<<<agrid, 256, 0, stream>>>(X1, row_off, edge_src, edge_w, n_nodes);
    gemm_mfma<1><<<ggrid, 256, 0, stream>>>(X1, Wpack, b0, b1, d_out, ntiles, gwaves);
}